// Round 8
// baseline (588.449 us; speedup 1.0000x reference)
//
#include <hip/hip_runtime.h>
#include <hip/hip_bf16.h>

#define N_NODES 50000
#define N_EDGES 800000
#define EP (N_EDGES + N_NODES)   // edges incl self loops
#define N_GRAPHS 64
#define F_DIM 128                // = F_IN = H*C
#define OUT_DIM 10
#define NB 391                   // ceil(50000/128) dst buckets
#define BCAP 2560                // bucket capacity (avg 2174, +8.5 sigma margin)

typedef __attribute__((ext_vector_type(8))) short short8;   // 8 bf16 (4 VGPRs)
typedef __attribute__((ext_vector_type(4))) float f32x4;

__device__ __forceinline__ unsigned int f2bf(float f) {
    unsigned int x; __builtin_memcpy(&x, &f, 4);
    return (x + 0x7fffu + ((x >> 16) & 1u)) >> 16;          // RNE
}
__device__ __forceinline__ float bf2f(unsigned int u16) {
    unsigned int x = u16 << 16;
    float f; __builtin_memcpy(&f, &x, 4); return f;
}

// ---------------- prep: zeros + W->Wt casts + weff_d ----------------
// grid = 128 x 256

__global__ __launch_bounds__(256) void prep_kernel(
    const float* __restrict__ W1, const float* __restrict__ W2,
    const float* __restrict__ Wd1, const float* __restrict__ ad1,
    const float* __restrict__ Wd2, const float* __restrict__ ad2,
    unsigned short* __restrict__ Wt1, unsigned short* __restrict__ Wt2,
    float* __restrict__ weffd1, float* __restrict__ weffd2,
    uint4* __restrict__ zero_bcur /*98*/, uint4* __restrict__ zero_sums /*2048*/) {
    int tid = blockIdx.x * 256 + threadIdx.x;
    if (tid < 98) zero_bcur[tid] = make_uint4(0, 0, 0, 0);
    else if (tid < 98 + 2048) zero_sums[tid - 98] = make_uint4(0, 0, 0, 0);
    // weff_d both layers: weffd[f*2+h] = sum_c Wd[f*128+h*64+c]*ad[h*64+c]
    if (tid < 512) {
        const float* Wd = (tid < 256) ? Wd1 : Wd2;
        const float* ad = (tid < 256) ? ad1 : ad2;
        float* wout = (tid < 256) ? weffd1 : weffd2;
        int i = tid & 255, f = i >> 1, h = i & 1;
        const float4* wr = (const float4*)(Wd + f * 128 + h * 64);
        const float4* av = (const float4*)(ad + h * 64);
        float s = 0.f;
        #pragma unroll
        for (int c = 0; c < 16; ++c) {
            float4 w = wr[c], a = av[c];
            s += w.x*a.x + w.y*a.y + w.z*a.z + w.w*a.w;
        }
        wout[f * 2 + h] = s;
    }
    // W cast + transpose: W[k][n] -> Wt[n][k]
    const float* W = (tid < 16384) ? W1 : W2;
    unsigned short* Wt = (tid < 16384) ? Wt1 : Wt2;
    int i = tid & 16383;
    int k = i >> 7, nn = i & 127;
    Wt[nn * 128 + k] = (unsigned short)f2bf(W[i]);
}

// ---------------- CSR build: bucket scatter + per-bucket sort ----------------

__global__ void scatter_kernel(const int* __restrict__ ei,
                               int* __restrict__ bcursor,
                               unsigned int* __restrict__ recs) {
    int e = blockIdx.x * blockDim.x + threadIdx.x;
    if (e >= EP) return;
    int src, dst;
    if (e < N_EDGES) { src = ei[e]; dst = ei[N_EDGES + e]; }
    else             { src = e - N_EDGES; dst = src; }
    int b = dst >> 7, dl = dst & 127;
    int pos = atomicAdd(&bcursor[b], 1);
    if (pos < BCAP)
        recs[(size_t)b * BCAP + pos] = ((unsigned)dl << 16) | (unsigned)src;
}

// one block per bucket: hist -> scan -> write eids (coalesced region) + (start,end)
__global__ __launch_bounds__(256) void bucketize_kernel(
    const unsigned int* __restrict__ recs, const int* __restrict__ bcursor,
    unsigned short* __restrict__ eids, int2* __restrict__ rsre, int n) {
    __shared__ int hist[128], excl[128], cur[128];
    int b = blockIdx.x, t = threadIdx.x;
    int cnt = bcursor[b]; if (cnt > BCAP) cnt = BCAP;
    if (t < 128) { hist[t] = 0; cur[t] = 0; }
    __syncthreads();
    const unsigned int* r = recs + (size_t)b * BCAP;
    for (int i = t; i < cnt; i += 256) atomicAdd(&hist[r[i] >> 16], 1);
    __syncthreads();
    if (t < 128) excl[t] = hist[t];
    __syncthreads();
    for (int off = 1; off < 128; off <<= 1) {       // inclusive scan
        int v = 0;
        if (t < 128 && t >= off) v = excl[t - off];
        __syncthreads();
        if (t < 128) excl[t] += v;
        __syncthreads();
    }
    int base = b * BCAP;
    if (t < 128) {
        int d = b * 128 + t;
        if (d < n) rsre[d] = make_int2(base + excl[t] - hist[t], base + excl[t]);
    }
    __syncthreads();
    for (int i = t; i < cnt; i += 256) {
        unsigned int rec = r[i];
        int dl = rec >> 16;
        int pos = atomicAdd(&cur[dl], 1);
        eids[(size_t)base + (excl[dl] - hist[dl]) + pos] = (unsigned short)(rec & 0xffffu);
    }
}

// ---------------- fused MFMA GEMM + attention scalars ----------------
// C = A @ W (bf16 out), a_s from f32 accumulators, a_d from A fragments.
// lane l = quad*16+lr; A-frag: row m0+lr, k = kb*32+quad*8+j; D: row m0+quad*4+r, col nt*16+lr.

__global__ __launch_bounds__(256) void gemm_fused_f32a_kernel(
    const float* __restrict__ A, const unsigned short* __restrict__ Wt,
    const float* __restrict__ att_s, const float* __restrict__ weffd,
    unsigned short* __restrict__ C, float* __restrict__ a_s, float* __restrict__ a_d, int n) {
    int t = threadIdx.x;
    int l = t & 63;
    int quad = l >> 4, lr = l & 15;
    int m0 = blockIdx.x * 64 + (t >> 6) * 16;
    int arow = m0 + lr; if (arow >= n) arow = n - 1;

    short8 afrag[4];
    float pd0 = 0.f, pd1 = 0.f;
    const float2* wd2 = (const float2*)weffd;
    #pragma unroll
    for (int kb = 0; kb < 4; ++kb) {
        const float4* ap = (const float4*)(A + (size_t)arow * 128 + kb * 32 + quad * 8);
        float4 a0 = ap[0], a1 = ap[1];
        int k0 = kb * 32 + quad * 8;
        float2 w0 = wd2[k0+0], w1 = wd2[k0+1], w2 = wd2[k0+2], w3 = wd2[k0+3];
        float2 w4 = wd2[k0+4], w5 = wd2[k0+5], w6 = wd2[k0+6], w7 = wd2[k0+7];
        pd0 += a0.x*w0.x + a0.y*w1.x + a0.z*w2.x + a0.w*w3.x
             + a1.x*w4.x + a1.y*w5.x + a1.z*w6.x + a1.w*w7.x;
        pd1 += a0.x*w0.y + a0.y*w1.y + a0.z*w2.y + a0.w*w3.y
             + a1.x*w4.y + a1.y*w5.y + a1.z*w6.y + a1.w*w7.y;
        short8 s;
        s[0] = (short)f2bf(a0.x); s[1] = (short)f2bf(a0.y);
        s[2] = (short)f2bf(a0.z); s[3] = (short)f2bf(a0.w);
        s[4] = (short)f2bf(a1.x); s[5] = (short)f2bf(a1.y);
        s[6] = (short)f2bf(a1.z); s[7] = (short)f2bf(a1.w);
        afrag[kb] = s;
    }
    pd0 += __shfl_xor(pd0, 16); pd0 += __shfl_xor(pd0, 32);
    pd1 += __shfl_xor(pd1, 16); pd1 += __shfl_xor(pd1, 32);
    if (l < 16 && m0 + lr < n) *(float2*)(a_d + (size_t)(m0 + lr) * 2) = make_float2(pd0, pd1);

    f32x4 acc[8] = {};
    #pragma unroll
    for (int nt = 0; nt < 8; ++nt) {
        #pragma unroll
        for (int kb = 0; kb < 4; ++kb) {
            short8 b = *(const short8*)(Wt + (size_t)(nt * 16 + lr) * 128 + kb * 32 + quad * 8);
            acc[nt] = __builtin_amdgcn_mfma_f32_16x16x32_bf16(afrag[kb], b, acc[nt], 0, 0, 0);
        }
    }
    float asv[8];
    #pragma unroll
    for (int nt = 0; nt < 8; ++nt) asv[nt] = att_s[nt * 16 + lr];
    float pa0[4] = {}, pa1[4] = {};
    #pragma unroll
    for (int nt = 0; nt < 8; ++nt)
        #pragma unroll
        for (int r = 0; r < 4; ++r) {
            if (nt < 4) pa0[r] += acc[nt][r] * asv[nt];
            else        pa1[r] += acc[nt][r] * asv[nt];
        }
    #pragma unroll
    for (int d = 1; d < 16; d <<= 1) {
        #pragma unroll
        for (int r = 0; r < 4; ++r) {
            pa0[r] += __shfl_xor(pa0[r], d);
            pa1[r] += __shfl_xor(pa1[r], d);
        }
    }
    if (lr == 0) {
        #pragma unroll
        for (int r = 0; r < 4; ++r) {
            int row = m0 + quad * 4 + r;
            if (row < n) *(float2*)(a_s + (size_t)row * 2) = make_float2(pa0[r], pa1[r]);
        }
    }
    #pragma unroll
    for (int nt = 0; nt < 8; ++nt)
        #pragma unroll
        for (int r = 0; r < 4; ++r) {
            int row = m0 + quad * 4 + r;
            if (row < n)
                C[(size_t)row * 128 + nt * 16 + lr] = (unsigned short)f2bf(acc[nt][r]);
        }
}

__global__ __launch_bounds__(256) void gemm_fused_bf16_kernel(
    const unsigned short* __restrict__ A, const unsigned short* __restrict__ Wt,
    const float* __restrict__ att_s, const float* __restrict__ weffd,
    unsigned short* __restrict__ C, float* __restrict__ a_s, float* __restrict__ a_d, int n) {
    int t = threadIdx.x;
    int l = t & 63;
    int quad = l >> 4, lr = l & 15;
    int m0 = blockIdx.x * 64 + (t >> 6) * 16;
    int arow = m0 + lr; if (arow >= n) arow = n - 1;

    short8 afrag[4];
    float pd0 = 0.f, pd1 = 0.f;
    const float2* wd2 = (const float2*)weffd;
    #pragma unroll
    for (int kb = 0; kb < 4; ++kb) {
        short8 s = *(const short8*)(A + (size_t)arow * 128 + kb * 32 + quad * 8);
        afrag[kb] = s;
        const unsigned int* u = (const unsigned int*)&s;
        int k0 = kb * 32 + quad * 8;
        #pragma unroll
        for (int d = 0; d < 4; ++d) {
            float x0 = __uint_as_float(u[d] << 16);
            float x1 = __uint_as_float(u[d] & 0xffff0000u);
            float2 wv0 = wd2[k0 + 2*d], wv1 = wd2[k0 + 2*d + 1];
            pd0 += x0 * wv0.x + x1 * wv1.x;
            pd1 += x0 * wv0.y + x1 * wv1.y;
        }
    }
    pd0 += __shfl_xor(pd0, 16); pd0 += __shfl_xor(pd0, 32);
    pd1 += __shfl_xor(pd1, 16); pd1 += __shfl_xor(pd1, 32);
    if (l < 16 && m0 + lr < n) *(float2*)(a_d + (size_t)(m0 + lr) * 2) = make_float2(pd0, pd1);

    f32x4 acc[8] = {};
    #pragma unroll
    for (int nt = 0; nt < 8; ++nt) {
        #pragma unroll
        for (int kb = 0; kb < 4; ++kb) {
            short8 b = *(const short8*)(Wt + (size_t)(nt * 16 + lr) * 128 + kb * 32 + quad * 8);
            acc[nt] = __builtin_amdgcn_mfma_f32_16x16x32_bf16(afrag[kb], b, acc[nt], 0, 0, 0);
        }
    }
    float asv[8];
    #pragma unroll
    for (int nt = 0; nt < 8; ++nt) asv[nt] = att_s[nt * 16 + lr];
    float pa0[4] = {}, pa1[4] = {};
    #pragma unroll
    for (int nt = 0; nt < 8; ++nt)
        #pragma unroll
        for (int r = 0; r < 4; ++r) {
            if (nt < 4) pa0[r] += acc[nt][r] * asv[nt];
            else        pa1[r] += acc[nt][r] * asv[nt];
        }
    #pragma unroll
    for (int d = 1; d < 16; d <<= 1) {
        #pragma unroll
        for (int r = 0; r < 4; ++r) {
            pa0[r] += __shfl_xor(pa0[r], d);
            pa1[r] += __shfl_xor(pa1[r], d);
        }
    }
    if (lr == 0) {
        #pragma unroll
        for (int r = 0; r < 4; ++r) {
            int row = m0 + quad * 4 + r;
            if (row < n) *(float2*)(a_s + (size_t)row * 2) = make_float2(pa0[r], pa1[r]);
        }
    }
    #pragma unroll
    for (int nt = 0; nt < 8; ++nt)
        #pragma unroll
        for (int r = 0; r < 4; ++r) {
            int row = m0 + quad * 4 + r;
            if (row < n)
                C[(size_t)row * 128 + nt * 16 + lr] = (unsigned short)f2bf(acc[nt][r]);
        }
}

// ---------------- edge aggregation: one wave per destination node ----------------
// 32-edge chunks; lanes 0-31 compute head-0 exp, lanes 32-63 head-1; unstabilized softmax.

__global__ __launch_bounds__(256) void aggregate_kernel(
    const int2* __restrict__ rsre, const unsigned short* __restrict__ eids,
    const float* __restrict__ a_s, const float* __restrict__ a_d,
    const unsigned int* __restrict__ xs32, const float* __restrict__ bias,
    unsigned int* __restrict__ out32, int n) {
    int wave = (int)((blockIdx.x * blockDim.x + threadIdx.x) >> 6);
    int lane = threadIdx.x & 63;
    if (wave >= n) return;
    int dstn = wave;
    int h    = lane >> 5;
    int j32  = lane & 31;
    int hoff = h << 5;
    int ch   = lane * 2;
    float2 advv = *(const float2*)(a_d + (size_t)dstn * 2);
    float adv = (h == 0) ? advv.x : advv.y;
    int2 rr = rsre[dstn];
    int row = rr.x, end = rr.y;

    float accA0 = 0.f, accA1 = 0.f, accB0 = 0.f, accB1 = 0.f, lsum = 0.f;
    for (int base = row; base < end; base += 32) {
        int rem = end - base;
        int k = rem < 32 ? rem : 32;
        int idx = base + (j32 < k ? j32 : k - 1);
        int eidv = (int)eids[idx];
        float2 as2 = *(const float2*)(a_s + (size_t)eidv * 2);
        float e = ((h == 0) ? as2.x : as2.y) + adv;
        e = (e > 0.f) ? e : 0.2f * e;
        float pme = (j32 < k) ? __expf(e) : 0.f;
        lsum += pme;
        int jb = 0;
        for (; jb + 4 <= k; jb += 4) {
            #pragma unroll
            for (int u = 0; u < 4; ++u) {
                int j = jb + u;
                int srcn = __shfl(eidv, j);
                float pj = __shfl(pme, j + hoff);
                unsigned int v = xs32[(size_t)srcn * 64 + lane];
                if (u & 1) {
                    accB0 += pj * __uint_as_float(v << 16);
                    accB1 += pj * __uint_as_float(v & 0xffff0000u);
                } else {
                    accA0 += pj * __uint_as_float(v << 16);
                    accA1 += pj * __uint_as_float(v & 0xffff0000u);
                }
            }
        }
        for (; jb < k; ++jb) {
            int srcn = __shfl(eidv, jb);
            float pj = __shfl(pme, jb + hoff);
            unsigned int v = xs32[(size_t)srcn * 64 + lane];
            accA0 += pj * __uint_as_float(v << 16);
            accA1 += pj * __uint_as_float(v & 0xffff0000u);
        }
    }
    #pragma unroll
    for (int d = 1; d <= 16; d <<= 1) lsum += __shfl_xor(lsum, d);
    float inv = 1.f / lsum;
    float o0 = fmaxf((accA0 + accB0) * inv + bias[ch], 0.f);
    float o1 = fmaxf((accA1 + accB1) * inv + bias[ch + 1], 0.f);
    out32[(size_t)dstn * 64 + lane] = f2bf(o0) | (f2bf(o1) << 16);
}

// ---------------- pool: partial sums + tiny final linear ----------------

#define POOL_CHUNK 128

__global__ __launch_bounds__(256) void pool_partial_kernel(
    const unsigned short* __restrict__ Hf, const int* __restrict__ batch,
    float* __restrict__ sums, int n) {
    int t = threadIdx.x;
    int c = t & 127, half = t >> 7;
    int start = blockIdx.x * POOL_CHUNK;
    int end = min(start + POOL_CHUNK, n);
    float acc = 0.f;
    int cur = -1;
    for (int i = start + half; i < end; i += 2) {
        int g = batch[i];
        if (g != cur) {
            if (cur >= 0) atomicAdd(&sums[cur * 128 + c], acc);
            acc = 0.f; cur = g;
        }
        acc += bf2f(Hf[(size_t)i * 128 + c]);
    }
    if (cur >= 0) atomicAdd(&sums[cur * 128 + c], acc);
}

__global__ void final_linear_kernel(const float* __restrict__ sums,
                                    const int* __restrict__ batch,
                                    const float* __restrict__ Wl, const float* __restrict__ bl,
                                    float* __restrict__ out, int n) {
    int t = blockIdx.x * blockDim.x + threadIdx.x;
    if (t >= N_GRAPHS * OUT_DIM) return;
    int g = t / OUT_DIM, o = t % OUT_DIM;
    int lo = 0, hi = n;
    while (lo < hi) { int mid = (lo + hi) >> 1; if (batch[mid] < g) lo = mid + 1; else hi = mid; }
    int s0 = lo; hi = n;
    while (lo < hi) { int mid = (lo + hi) >> 1; if (batch[mid] < g + 1) lo = mid + 1; else hi = mid; }
    float cnt = (float)(lo - s0);
    float inv = 1.f / fmaxf(cnt, 1.f);
    float s = bl[o];
    for (int c = 0; c < 128; ++c) s += sums[g * 128 + c] * inv * Wl[c * OUT_DIM + o];
    out[g * OUT_DIM + o] = s;
}

// ---------------- launch ----------------

extern "C" void kernel_launch(void* const* d_in, const int* in_sizes, int n_in,
                              void* d_out, int out_size, void* d_ws, size_t ws_size,
                              hipStream_t stream) {
    const float* x    = (const float*)d_in[0];
    const int*   ei   = (const int*)d_in[1];
    const int*   batch= (const int*)d_in[2];
    const float* Ws1  = (const float*)d_in[3];
    const float* Wd1  = (const float*)d_in[4];
    const float* as1  = (const float*)d_in[5];
    const float* ad1  = (const float*)d_in[6];
    const float* b1   = (const float*)d_in[7];
    const float* Ws2  = (const float*)d_in[8];
    const float* Wd2  = (const float*)d_in[9];
    const float* as2  = (const float*)d_in[10];
    const float* ad2  = (const float*)d_in[11];
    const float* b2   = (const float*)d_in[12];
    const float* Wl   = (const float*)d_in[13];
    const float* bl   = (const float*)d_in[14];
    float* out = (float*)d_out;

    char* p = (char*)d_ws;
    auto alloc = [&](size_t bytes) {
        void* r = (void*)p;
        p += (bytes + 255) & ~(size_t)255;
        return r;
    };
    int* bcursor  = (int*)alloc(sizeof(int) * 98 * 4);            // 392 >= NB, zeroed as uint4
    unsigned int* recs = (unsigned int*)alloc(sizeof(int) * (size_t)NB * BCAP);
    unsigned short* eids = (unsigned short*)alloc(sizeof(short) * (size_t)NB * BCAP);
    int2* rsre    = (int2*)alloc(sizeof(int2) * N_NODES);
    float* a_s    = (float*)alloc(sizeof(float) * N_NODES * 2);
    float* a_d    = (float*)alloc(sizeof(float) * N_NODES * 2);
    float* sums   = (float*)alloc(sizeof(float) * N_GRAPHS * 128);
    float* weffd1 = (float*)alloc(sizeof(float) * 128 * 2);
    float* weffd2 = (float*)alloc(sizeof(float) * 128 * 2);
    unsigned short* Wt1  = (unsigned short*)alloc(sizeof(short) * 128 * 128);
    unsigned short* Wt2  = (unsigned short*)alloc(sizeof(short) * 128 * 128);
    unsigned short* bufA = (unsigned short*)alloc(sizeof(short) * (size_t)N_NODES * F_DIM); // xs
    unsigned short* bufB = (unsigned short*)alloc(sizeof(short) * (size_t)N_NODES * F_DIM); // h

    // ---- prep + CSR build ----
    prep_kernel<<<128, 256, 0, stream>>>(Ws1, Ws2, Wd1, ad1, Wd2, ad2,
                                         Wt1, Wt2, weffd1, weffd2,
                                         (uint4*)bcursor, (uint4*)sums);
    scatter_kernel<<<(EP + 255) / 256, 256, 0, stream>>>(ei, bcursor, recs);
    bucketize_kernel<<<NB, 256, 0, stream>>>(recs, bcursor, eids, rsre, N_NODES);

    const int gemm_grid = (N_NODES + 63) / 64;
    const int agg_grid  = (N_NODES + 3) / 4;

    // ---- layer 1 ----
    gemm_fused_f32a_kernel<<<gemm_grid, 256, 0, stream>>>(x, Wt1, as1, weffd1,
                                                          bufA, a_s, a_d, N_NODES);
    aggregate_kernel<<<agg_grid, 256, 0, stream>>>(rsre, eids, a_s, a_d,
                                                   (const unsigned int*)bufA, b1,
                                                   (unsigned int*)bufB, N_NODES);

    // ---- layer 2 ----
    gemm_fused_bf16_kernel<<<gemm_grid, 256, 0, stream>>>(bufB, Wt2, as2, weffd2,
                                                          bufA, a_s, a_d, N_NODES);
    aggregate_kernel<<<agg_grid, 256, 0, stream>>>(rsre, eids, a_s, a_d,
                                                   (const unsigned int*)bufA, b2,
                                                   (unsigned int*)bufB, N_NODES);

    // ---- pool + linear ----
    pool_partial_kernel<<<(N_NODES + POOL_CHUNK - 1) / POOL_CHUNK, 256, 0, stream>>>(bufB, batch, sums, N_NODES);
    final_linear_kernel<<<(N_GRAPHS * OUT_DIM + 255) / 256, 256, 0, stream>>>(sums, batch, Wl, bl, out, N_NODES);
}

// Round 10
// 325.009 us; speedup vs baseline: 1.8106x; 1.8106x over previous
//
#include <hip/hip_runtime.h>
#include <hip/hip_bf16.h>

#define N_NODES 50000
#define N_EDGES 800000
#define EP (N_EDGES + N_NODES)   // edges incl self loops
#define N_GRAPHS 64
#define F_DIM 128                // = F_IN = H*C
#define OUT_DIM 10
#define NB 391                   // ceil(50000/128) dst buckets
#define NREP 64                  // cursor replicas; rep = e & 63 (decorrelated from dst)
#define SUBCAP 80                // capacity per (bucket,replica): E=34, +8 sigma
#define EIDS_CAP 2560            // per-bucket eids capacity: E=2174, +8.5 sigma

typedef __attribute__((ext_vector_type(8))) short short8;   // 8 bf16 (4 VGPRs)
typedef __attribute__((ext_vector_type(4))) float f32x4;

__device__ __forceinline__ unsigned int f2bf(float f) {
    unsigned int x; __builtin_memcpy(&x, &f, 4);
    return (x + 0x7fffu + ((x >> 16) & 1u)) >> 16;          // RNE
}
__device__ __forceinline__ float bf2f(unsigned int u16) {
    unsigned int x = u16 << 16;
    float f; __builtin_memcpy(&f, &x, 4); return f;
}

// ---------------- prep: zeros + W->Wt casts + weff_d ----------------
// grid = 128 x 256 = 32768 threads

__global__ __launch_bounds__(256) void prep_kernel(
    const float* __restrict__ W1, const float* __restrict__ W2,
    const float* __restrict__ Wd1, const float* __restrict__ ad1,
    const float* __restrict__ Wd2, const float* __restrict__ ad2,
    unsigned short* __restrict__ Wt1, unsigned short* __restrict__ Wt2,
    float* __restrict__ weffd1, float* __restrict__ weffd2,
    uint4* __restrict__ zero_bcur /*6256*/, uint4* __restrict__ zero_sums /*2048*/) {
    int tid = blockIdx.x * 256 + threadIdx.x;
    if (tid < 6256) zero_bcur[tid] = make_uint4(0, 0, 0, 0);
    else if (tid < 6256 + 2048) zero_sums[tid - 6256] = make_uint4(0, 0, 0, 0);
    // weff_d both layers: weffd[f*2+h] = sum_c Wd[f*128+h*64+c]*ad[h*64+c]
    if (tid < 512) {
        const float* Wd = (tid < 256) ? Wd1 : Wd2;
        const float* ad = (tid < 256) ? ad1 : ad2;
        float* wout = (tid < 256) ? weffd1 : weffd2;
        int i = tid & 255, f = i >> 1, h = i & 1;
        const float4* wr = (const float4*)(Wd + f * 128 + h * 64);
        const float4* av = (const float4*)(ad + h * 64);
        float s = 0.f;
        #pragma unroll
        for (int c = 0; c < 16; ++c) {
            float4 w = wr[c], a = av[c];
            s += w.x*a.x + w.y*a.y + w.z*a.z + w.w*a.w;
        }
        wout[f * 2 + h] = s;
    }
    // W cast + transpose: W[k][n] -> Wt[n][k]
    const float* W = (tid < 16384) ? W1 : W2;
    unsigned short* Wt = (tid < 16384) ? Wt1 : Wt2;
    int i = tid & 16383;
    int k = i >> 7, nn = i & 127;
    Wt[nn * 128 + k] = (unsigned short)f2bf(W[i]);
}

// ---------------- CSR build: replicated-cursor bucket scatter + per-bucket sort ----------------
// bcursor layout [rep][NB]; recs layout [b][rep][SUBCAP]; recs ALIASES bufA (dead until gemm1).

__global__ void scatter_kernel(const int* __restrict__ ei,
                               int* __restrict__ bcursor,
                               unsigned int* __restrict__ recs) {
    int e = blockIdx.x * blockDim.x + threadIdx.x;
    if (e >= EP) return;
    int src, dst;
    if (e < N_EDGES) { src = ei[e]; dst = ei[N_EDGES + e]; }
    else             { src = e - N_EDGES; dst = src; }
    int b = dst >> 7, dl = dst & 127;
    int rep = e & (NREP - 1);   // per-lane; decorrelates consecutive (self-loop) dsts
    int pos = atomicAdd(&bcursor[rep * NB + b], 1);
    if (pos < SUBCAP)
        recs[((size_t)b * NREP + rep) * SUBCAP + pos] = ((unsigned)dl << 16) | (unsigned)src;
}

// one block per bucket: concat 64 sub-segments -> hist -> scan -> eids + (start,end)
__global__ __launch_bounds__(256) void bucketize_kernel(
    const unsigned int* __restrict__ recs, const int* __restrict__ bcursor,
    unsigned short* __restrict__ eids, int2* __restrict__ rsre, int n) {
    __shared__ int ssub[NREP + 1];     // prefix of sub-counts
    __shared__ int hist[128], excl[128], cur[128];
    __shared__ unsigned int srec[EIDS_CAP];
    int b = blockIdx.x, t = threadIdx.x;
    if (t < 128) { hist[t] = 0; cur[t] = 0; }
    if (t < NREP) {
        int c = bcursor[t * NB + b]; if (c > SUBCAP) c = SUBCAP;
        int incl = c;                              // wave-level inclusive scan (NREP=64)
        #pragma unroll
        for (int d = 1; d < 64; d <<= 1) { int o = __shfl_up(incl, d, 64); if (t >= d) incl += o; }
        ssub[t + 1] = incl;
        if (t == 0) ssub[0] = 0;
    }
    __syncthreads();
    int total = ssub[NREP]; if (total > EIDS_CAP) total = EIDS_CAP;
    const unsigned int* rb = recs + (size_t)b * NREP * SUBCAP;
    for (int i = t; i < total; i += 256) {
        int lo = 0, hi = NREP;                     // largest rep with ssub[rep] <= i
        while (lo + 1 < hi) { int mid = (lo + hi) >> 1; if (ssub[mid] <= i) lo = mid; else hi = mid; }
        unsigned int rec = rb[lo * SUBCAP + (i - ssub[lo])];
        srec[i] = rec;
        atomicAdd(&hist[rec >> 16], 1);
    }
    __syncthreads();
    if (t < 128) excl[t] = hist[t];
    __syncthreads();
    for (int off = 1; off < 128; off <<= 1) {      // inclusive scan of per-dst counts
        int v = 0;
        if (t < 128 && t >= off) v = excl[t - off];
        __syncthreads();
        if (t < 128) excl[t] += v;
        __syncthreads();
    }
    int base = b * EIDS_CAP;
    if (t < 128) {
        int d = b * 128 + t;
        if (d < n) rsre[d] = make_int2(base + excl[t] - hist[t], base + excl[t]);
    }
    __syncthreads();
    for (int i = t; i < total; i += 256) {
        unsigned int rec = srec[i];
        int dl = rec >> 16;
        int pos = atomicAdd(&cur[dl], 1);
        eids[(size_t)base + (excl[dl] - hist[dl]) + pos] = (unsigned short)(rec & 0xffffu);
    }
}

// ---------------- fused MFMA GEMM + attention scalars ----------------
// C = A @ W (bf16 out), a_s from f32 accumulators, a_d from A fragments.
// lane l = quad*16+lr; A-frag: row m0+lr, k = kb*32+quad*8+j; D: row m0+quad*4+r, col nt*16+lr.

__global__ __launch_bounds__(256) void gemm_fused_f32a_kernel(
    const float* __restrict__ A, const unsigned short* __restrict__ Wt,
    const float* __restrict__ att_s, const float* __restrict__ weffd,
    unsigned short* __restrict__ C, float* __restrict__ a_s, float* __restrict__ a_d, int n) {
    int t = threadIdx.x;
    int l = t & 63;
    int quad = l >> 4, lr = l & 15;
    int m0 = blockIdx.x * 64 + (t >> 6) * 16;
    int arow = m0 + lr; if (arow >= n) arow = n - 1;

    short8 afrag[4];
    float pd0 = 0.f, pd1 = 0.f;
    const float2* wd2 = (const float2*)weffd;
    #pragma unroll
    for (int kb = 0; kb < 4; ++kb) {
        const float4* ap = (const float4*)(A + (size_t)arow * 128 + kb * 32 + quad * 8);
        float4 a0 = ap[0], a1 = ap[1];
        int k0 = kb * 32 + quad * 8;
        float2 w0 = wd2[k0+0], w1 = wd2[k0+1], w2 = wd2[k0+2], w3 = wd2[k0+3];
        float2 w4 = wd2[k0+4], w5 = wd2[k0+5], w6 = wd2[k0+6], w7 = wd2[k0+7];
        pd0 += a0.x*w0.x + a0.y*w1.x + a0.z*w2.x + a0.w*w3.x
             + a1.x*w4.x + a1.y*w5.x + a1.z*w6.x + a1.w*w7.x;
        pd1 += a0.x*w0.y + a0.y*w1.y + a0.z*w2.y + a0.w*w3.y
             + a1.x*w4.y + a1.y*w5.y + a1.z*w6.y + a1.w*w7.y;
        short8 s;
        s[0] = (short)f2bf(a0.x); s[1] = (short)f2bf(a0.y);
        s[2] = (short)f2bf(a0.z); s[3] = (short)f2bf(a0.w);
        s[4] = (short)f2bf(a1.x); s[5] = (short)f2bf(a1.y);
        s[6] = (short)f2bf(a1.z); s[7] = (short)f2bf(a1.w);
        afrag[kb] = s;
    }
    pd0 += __shfl_xor(pd0, 16); pd0 += __shfl_xor(pd0, 32);
    pd1 += __shfl_xor(pd1, 16); pd1 += __shfl_xor(pd1, 32);
    if (l < 16 && m0 + lr < n) *(float2*)(a_d + (size_t)(m0 + lr) * 2) = make_float2(pd0, pd1);

    f32x4 acc[8] = {};
    #pragma unroll
    for (int nt = 0; nt < 8; ++nt) {
        #pragma unroll
        for (int kb = 0; kb < 4; ++kb) {
            short8 b = *(const short8*)(Wt + (size_t)(nt * 16 + lr) * 128 + kb * 32 + quad * 8);
            acc[nt] = __builtin_amdgcn_mfma_f32_16x16x32_bf16(afrag[kb], b, acc[nt], 0, 0, 0);
        }
    }
    float asv[8];
    #pragma unroll
    for (int nt = 0; nt < 8; ++nt) asv[nt] = att_s[nt * 16 + lr];
    float pa0[4] = {}, pa1[4] = {};
    #pragma unroll
    for (int nt = 0; nt < 8; ++nt)
        #pragma unroll
        for (int r = 0; r < 4; ++r) {
            if (nt < 4) pa0[r] += acc[nt][r] * asv[nt];
            else        pa1[r] += acc[nt][r] * asv[nt];
        }
    #pragma unroll
    for (int d = 1; d < 16; d <<= 1) {
        #pragma unroll
        for (int r = 0; r < 4; ++r) {
            pa0[r] += __shfl_xor(pa0[r], d);
            pa1[r] += __shfl_xor(pa1[r], d);
        }
    }
    if (lr == 0) {
        #pragma unroll
        for (int r = 0; r < 4; ++r) {
            int row = m0 + quad * 4 + r;
            if (row < n) *(float2*)(a_s + (size_t)row * 2) = make_float2(pa0[r], pa1[r]);
        }
    }
    #pragma unroll
    for (int nt = 0; nt < 8; ++nt)
        #pragma unroll
        for (int r = 0; r < 4; ++r) {
            int row = m0 + quad * 4 + r;
            if (row < n)
                C[(size_t)row * 128 + nt * 16 + lr] = (unsigned short)f2bf(acc[nt][r]);
        }
}

__global__ __launch_bounds__(256) void gemm_fused_bf16_kernel(
    const unsigned short* __restrict__ A, const unsigned short* __restrict__ Wt,
    const float* __restrict__ att_s, const float* __restrict__ weffd,
    unsigned short* __restrict__ C, float* __restrict__ a_s, float* __restrict__ a_d, int n) {
    int t = threadIdx.x;
    int l = t & 63;
    int quad = l >> 4, lr = l & 15;
    int m0 = blockIdx.x * 64 + (t >> 6) * 16;
    int arow = m0 + lr; if (arow >= n) arow = n - 1;

    short8 afrag[4];
    float pd0 = 0.f, pd1 = 0.f;
    const float2* wd2 = (const float2*)weffd;
    #pragma unroll
    for (int kb = 0; kb < 4; ++kb) {
        short8 s = *(const short8*)(A + (size_t)arow * 128 + kb * 32 + quad * 8);
        afrag[kb] = s;
        const unsigned int* u = (const unsigned int*)&s;
        int k0 = kb * 32 + quad * 8;
        #pragma unroll
        for (int d = 0; d < 4; ++d) {
            float x0 = __uint_as_float(u[d] << 16);
            float x1 = __uint_as_float(u[d] & 0xffff0000u);
            float2 wv0 = wd2[k0 + 2*d], wv1 = wd2[k0 + 2*d + 1];
            pd0 += x0 * wv0.x + x1 * wv1.x;
            pd1 += x0 * wv0.y + x1 * wv1.y;
        }
    }
    pd0 += __shfl_xor(pd0, 16); pd0 += __shfl_xor(pd0, 32);
    pd1 += __shfl_xor(pd1, 16); pd1 += __shfl_xor(pd1, 32);
    if (l < 16 && m0 + lr < n) *(float2*)(a_d + (size_t)(m0 + lr) * 2) = make_float2(pd0, pd1);

    f32x4 acc[8] = {};
    #pragma unroll
    for (int nt = 0; nt < 8; ++nt) {
        #pragma unroll
        for (int kb = 0; kb < 4; ++kb) {
            short8 b = *(const short8*)(Wt + (size_t)(nt * 16 + lr) * 128 + kb * 32 + quad * 8);
            acc[nt] = __builtin_amdgcn_mfma_f32_16x16x32_bf16(afrag[kb], b, acc[nt], 0, 0, 0);
        }
    }
    float asv[8];
    #pragma unroll
    for (int nt = 0; nt < 8; ++nt) asv[nt] = att_s[nt * 16 + lr];
    float pa0[4] = {}, pa1[4] = {};
    #pragma unroll
    for (int nt = 0; nt < 8; ++nt)
        #pragma unroll
        for (int r = 0; r < 4; ++r) {
            if (nt < 4) pa0[r] += acc[nt][r] * asv[nt];
            else        pa1[r] += acc[nt][r] * asv[nt];
        }
    #pragma unroll
    for (int d = 1; d < 16; d <<= 1) {
        #pragma unroll
        for (int r = 0; r < 4; ++r) {
            pa0[r] += __shfl_xor(pa0[r], d);
            pa1[r] += __shfl_xor(pa1[r], d);
        }
    }
    if (lr == 0) {
        #pragma unroll
        for (int r = 0; r < 4; ++r) {
            int row = m0 + quad * 4 + r;
            if (row < n) *(float2*)(a_s + (size_t)row * 2) = make_float2(pa0[r], pa1[r]);
        }
    }
    #pragma unroll
    for (int nt = 0; nt < 8; ++nt)
        #pragma unroll
        for (int r = 0; r < 4; ++r) {
            int row = m0 + quad * 4 + r;
            if (row < n)
                C[(size_t)row * 128 + nt * 16 + lr] = (unsigned short)f2bf(acc[nt][r]);
        }
}

// ---------------- edge aggregation: one wave per destination node ----------------
// 32-edge chunks; lanes 0-31 compute head-0 exp, lanes 32-63 head-1; unstabilized softmax.

__global__ __launch_bounds__(256) void aggregate_kernel(
    const int2* __restrict__ rsre, const unsigned short* __restrict__ eids,
    const float* __restrict__ a_s, const float* __restrict__ a_d,
    const unsigned int* __restrict__ xs32, const float* __restrict__ bias,
    unsigned int* __restrict__ out32, int n) {
    int wave = (int)((blockIdx.x * blockDim.x + threadIdx.x) >> 6);
    int lane = threadIdx.x & 63;
    if (wave >= n) return;
    int dstn = wave;
    int h    = lane >> 5;
    int j32  = lane & 31;
    int hoff = h << 5;
    int ch   = lane * 2;
    float2 advv = *(const float2*)(a_d + (size_t)dstn * 2);
    float adv = (h == 0) ? advv.x : advv.y;
    int2 rr = rsre[dstn];
    int row = rr.x, end = rr.y;

    float accA0 = 0.f, accA1 = 0.f, accB0 = 0.f, accB1 = 0.f, lsum = 0.f;
    for (int base = row; base < end; base += 32) {
        int rem = end - base;
        int k = rem < 32 ? rem : 32;
        int idx = base + (j32 < k ? j32 : k - 1);
        int eidv = (int)eids[idx];
        float2 as2 = *(const float2*)(a_s + (size_t)eidv * 2);
        float e = ((h == 0) ? as2.x : as2.y) + adv;
        e = (e > 0.f) ? e : 0.2f * e;
        float pme = (j32 < k) ? __expf(e) : 0.f;
        lsum += pme;
        int jb = 0;
        for (; jb + 4 <= k; jb += 4) {
            #pragma unroll
            for (int u = 0; u < 4; ++u) {
                int j = jb + u;
                int srcn = __shfl(eidv, j);
                float pj = __shfl(pme, j + hoff);
                unsigned int v = xs32[(size_t)srcn * 64 + lane];
                if (u & 1) {
                    accB0 += pj * __uint_as_float(v << 16);
                    accB1 += pj * __uint_as_float(v & 0xffff0000u);
                } else {
                    accA0 += pj * __uint_as_float(v << 16);
                    accA1 += pj * __uint_as_float(v & 0xffff0000u);
                }
            }
        }
        for (; jb < k; ++jb) {
            int srcn = __shfl(eidv, jb);
            float pj = __shfl(pme, jb + hoff);
            unsigned int v = xs32[(size_t)srcn * 64 + lane];
            accA0 += pj * __uint_as_float(v << 16);
            accA1 += pj * __uint_as_float(v & 0xffff0000u);
        }
    }
    #pragma unroll
    for (int d = 1; d <= 16; d <<= 1) lsum += __shfl_xor(lsum, d);
    float inv = 1.f / lsum;
    float o0 = fmaxf((accA0 + accB0) * inv + bias[ch], 0.f);
    float o1 = fmaxf((accA1 + accB1) * inv + bias[ch + 1], 0.f);
    out32[(size_t)dstn * 64 + lane] = f2bf(o0) | (f2bf(o1) << 16);
}

// ---------------- pool: partial sums + tiny final linear ----------------

#define POOL_CHUNK 128

__global__ __launch_bounds__(256) void pool_partial_kernel(
    const unsigned short* __restrict__ Hf, const int* __restrict__ batch,
    float* __restrict__ sums, int n) {
    int t = threadIdx.x;
    int c = t & 127, half = t >> 7;
    int start = blockIdx.x * POOL_CHUNK;
    int end = min(start + POOL_CHUNK, n);
    float acc = 0.f;
    int cur = -1;
    for (int i = start + half; i < end; i += 2) {
        int g = batch[i];
        if (g != cur) {
            if (cur >= 0) atomicAdd(&sums[cur * 128 + c], acc);
            acc = 0.f; cur = g;
        }
        acc += bf2f(Hf[(size_t)i * 128 + c]);
    }
    if (cur >= 0) atomicAdd(&sums[cur * 128 + c], acc);
}

__global__ void final_linear_kernel(const float* __restrict__ sums,
                                    const int* __restrict__ batch,
                                    const float* __restrict__ Wl, const float* __restrict__ bl,
                                    float* __restrict__ out, int n) {
    int t = blockIdx.x * blockDim.x + threadIdx.x;
    if (t >= N_GRAPHS * OUT_DIM) return;
    int g = t / OUT_DIM, o = t % OUT_DIM;
    int lo = 0, hi = n;
    while (lo < hi) { int mid = (lo + hi) >> 1; if (batch[mid] < g) lo = mid + 1; else hi = mid; }
    int s0 = lo; hi = n;
    while (lo < hi) { int mid = (lo + hi) >> 1; if (batch[mid] < g + 1) lo = mid + 1; else hi = mid; }
    float cnt = (float)(lo - s0);
    float inv = 1.f / fmaxf(cnt, 1.f);
    float s = bl[o];
    for (int c = 0; c < 128; ++c) s += sums[g * 128 + c] * inv * Wl[c * OUT_DIM + o];
    out[g * OUT_DIM + o] = s;
}

// ---------------- launch ----------------

extern "C" void kernel_launch(void* const* d_in, const int* in_sizes, int n_in,
                              void* d_out, int out_size, void* d_ws, size_t ws_size,
                              hipStream_t stream) {
    const float* x    = (const float*)d_in[0];
    const int*   ei   = (const int*)d_in[1];
    const int*   batch= (const int*)d_in[2];
    const float* Ws1  = (const float*)d_in[3];
    const float* Wd1  = (const float*)d_in[4];
    const float* as1  = (const float*)d_in[5];
    const float* ad1  = (const float*)d_in[6];
    const float* b1   = (const float*)d_in[7];
    const float* Ws2  = (const float*)d_in[8];
    const float* Wd2  = (const float*)d_in[9];
    const float* as2  = (const float*)d_in[10];
    const float* ad2  = (const float*)d_in[11];
    const float* b2   = (const float*)d_in[12];
    const float* Wl   = (const float*)d_in[13];
    const float* bl   = (const float*)d_in[14];
    float* out = (float*)d_out;

    // Workspace budget note: total static allocs ~29.1 MB (R8's 32.5 MB passed;
    // R9's 42.7 MB aborted -> keep under the proven ceiling).
    char* p = (char*)d_ws;
    auto alloc = [&](size_t bytes) {
        void* r = (void*)p;
        p += (bytes + 255) & ~(size_t)255;
        return r;
    };
    int* bcursor  = (int*)alloc(sizeof(int) * NREP * NB);                      // 100 KB
    unsigned short* eids = (unsigned short*)alloc(sizeof(short) * (size_t)NB * EIDS_CAP); // 2.0 MB
    int2* rsre    = (int2*)alloc(sizeof(int2) * N_NODES);                      // 0.4 MB
    float* a_s    = (float*)alloc(sizeof(float) * N_NODES * 2);
    float* a_d    = (float*)alloc(sizeof(float) * N_NODES * 2);
    float* sums   = (float*)alloc(sizeof(float) * N_GRAPHS * 128);
    float* weffd1 = (float*)alloc(sizeof(float) * 128 * 2);
    float* weffd2 = (float*)alloc(sizeof(float) * 128 * 2);
    unsigned short* Wt1  = (unsigned short*)alloc(sizeof(short) * 128 * 128);
    unsigned short* Wt2  = (unsigned short*)alloc(sizeof(short) * 128 * 128);
    unsigned short* bufA = (unsigned short*)alloc(sizeof(short) * (size_t)N_NODES * F_DIM); // 12.8 MB
    unsigned short* bufB = (unsigned short*)alloc(sizeof(short) * (size_t)N_NODES * F_DIM); // 12.8 MB
    // recs (8.0 MB) aliases bufA: dead before gemm1 writes bufA (stream-ordered).
    unsigned int* recs = (unsigned int*)bufA;   // NB*NREP*SUBCAP*4 = 8.0 MB <= 12.8 MB

    // ---- prep + CSR build ----
    prep_kernel<<<128, 256, 0, stream>>>(Ws1, Ws2, Wd1, ad1, Wd2, ad2,
                                         Wt1, Wt2, weffd1, weffd2,
                                         (uint4*)bcursor, (uint4*)sums);
    scatter_kernel<<<(EP + 255) / 256, 256, 0, stream>>>(ei, bcursor, recs);
    bucketize_kernel<<<NB, 256, 0, stream>>>(recs, bcursor, eids, rsre, N_NODES);

    const int gemm_grid = (N_NODES + 63) / 64;
    const int agg_grid  = (N_NODES + 3) / 4;

    // ---- layer 1 ----
    gemm_fused_f32a_kernel<<<gemm_grid, 256, 0, stream>>>(x, Wt1, as1, weffd1,
                                                          bufA, a_s, a_d, N_NODES);
    aggregate_kernel<<<agg_grid, 256, 0, stream>>>(rsre, eids, a_s, a_d,
                                                   (const unsigned int*)bufA, b1,
                                                   (unsigned int*)bufB, N_NODES);

    // ---- layer 2 ----
    gemm_fused_bf16_kernel<<<gemm_grid, 256, 0, stream>>>(bufB, Wt2, as2, weffd2,
                                                          bufA, a_s, a_d, N_NODES);
    aggregate_kernel<<<agg_grid, 256, 0, stream>>>(rsre, eids, a_s, a_d,
                                                   (const unsigned int*)bufA, b2,
                                                   (unsigned int*)bufB, N_NODES);

    // ---- pool + linear ----
    pool_partial_kernel<<<(N_NODES + POOL_CHUNK - 1) / POOL_CHUNK, 256, 0, stream>>>(bufB, batch, sums, N_NODES);
    final_linear_kernel<<<(N_GRAPHS * OUT_DIM + 255) / 256, 256, 0, stream>>>(sums, batch, Wl, bl, out, N_NODES);
}

// Round 11
// 277.647 us; speedup vs baseline: 2.1194x; 1.1706x over previous
//
#include <hip/hip_runtime.h>
#include <hip/hip_bf16.h>

#define N_NODES 50000
#define N_EDGES 800000
#define EP (N_EDGES + N_NODES)
#define N_GRAPHS 64
#define F_DIM 128
#define OUT_DIM 10
#define NB 391                   // dst buckets of 128
#define NREP 8                   // cursor replicas: rep = blockIdx & 7
#define SUBCAP 384               // per (bucket,rep): E=256, +8 sigma
#define EIDS_CAP 2560            // per-bucket: E=2174 (incl selfloops), +8.6 sigma
#define SC_EDGES 4096            // edges per scatter block
#define SC_BLOCKS ((N_EDGES + SC_EDGES - 1) / SC_EDGES)   // 196

typedef __attribute__((ext_vector_type(8))) short short8;
typedef __attribute__((ext_vector_type(4))) float f32x4;

__device__ __forceinline__ unsigned int f2bf(float f) {
    unsigned int x; __builtin_memcpy(&x, &f, 4);
    return (x + 0x7fffu + ((x >> 16) & 1u)) >> 16;          // RNE
}
__device__ __forceinline__ float bf2f(unsigned int u16) {
    unsigned int x = u16 << 16;
    float f; __builtin_memcpy(&f, &x, 4); return f;
}

// ---------------- prep: zeros + W->Wt casts + weff_d ----------------

__global__ __launch_bounds__(256) void prep_kernel(
    const float* __restrict__ W1, const float* __restrict__ W2,
    const float* __restrict__ Wd1, const float* __restrict__ ad1,
    const float* __restrict__ Wd2, const float* __restrict__ ad2,
    unsigned short* __restrict__ Wt1, unsigned short* __restrict__ Wt2,
    float* __restrict__ weffd1, float* __restrict__ weffd2,
    uint4* __restrict__ zero_bcur /*782*/, uint4* __restrict__ zero_sums /*2048*/) {
    int tid = blockIdx.x * 256 + threadIdx.x;
    if (tid < 782) zero_bcur[tid] = make_uint4(0, 0, 0, 0);
    else if (tid < 782 + 2048) zero_sums[tid - 782] = make_uint4(0, 0, 0, 0);
    if (tid < 512) {
        const float* Wd = (tid < 256) ? Wd1 : Wd2;
        const float* ad = (tid < 256) ? ad1 : ad2;
        float* wout = (tid < 256) ? weffd1 : weffd2;
        int i = tid & 255, f = i >> 1, h = i & 1;
        const float4* wr = (const float4*)(Wd + f * 128 + h * 64);
        const float4* av = (const float4*)(ad + h * 64);
        float s = 0.f;
        #pragma unroll
        for (int c = 0; c < 16; ++c) {
            float4 w = wr[c], a = av[c];
            s += w.x*a.x + w.y*a.y + w.z*a.z + w.w*a.w;
        }
        wout[f * 2 + h] = s;
    }
    const float* W = (tid < 16384) ? W1 : W2;
    unsigned short* Wt = (tid < 16384) ? Wt1 : Wt2;
    int i = tid & 16383;
    int k = i >> 7, nn = i & 127;
    Wt[nn * 128 + k] = (unsigned short)f2bf(W[i]);
}

// ---------------- CSR build: LDS counting-sort scatter (coalesced run writes) ----------------
// Real edges only (self-loops injected in bucketize). rec = (b<<23)|(dl<<16)|src.
// recs ALIASES bufA (dead until gemm1 writes it).

__global__ __launch_bounds__(1024) void scatter_kernel(const int* __restrict__ ei,
                                                       int* __restrict__ bcursor,
                                                       unsigned int* __restrict__ recs) {
    __shared__ unsigned int srec[SC_EDGES];   // 16 KB
    __shared__ int hist[NB], lcur[NB], gpos[NB];
    __shared__ int excl[512];
    int t = threadIdx.x;
    int base = blockIdx.x * SC_EDGES;
    int rep = blockIdx.x & (NREP - 1);
    for (int i = t; i < NB; i += 1024) { hist[i] = 0; lcur[i] = 0; }
    __syncthreads();
    unsigned int rec_[4]; int have[4];
    #pragma unroll
    for (int j = 0; j < 4; ++j) {
        int i = base + j * 1024 + t;
        have[j] = (i < N_EDGES);
        if (have[j]) {
            int src = ei[i], dst = ei[N_EDGES + i];
            int b = dst >> 7;
            rec_[j] = ((unsigned)b << 23) | ((unsigned)(dst & 127) << 16) | (unsigned)src;
            atomicAdd(&hist[b], 1);
        }
    }
    __syncthreads();
    if (t < 512) excl[t] = (t < NB) ? hist[t] : 0;
    __syncthreads();
    for (int off = 1; off < 512; off <<= 1) {        // inclusive scan
        int v = 0;
        if (t < 512 && t >= off) v = excl[t - off];
        __syncthreads();
        if (t < 512) excl[t] += v;
        __syncthreads();
    }
    if (t < NB && hist[t] > 0) gpos[t] = atomicAdd(&bcursor[rep * NB + t], hist[t]);
    __syncthreads();
    #pragma unroll
    for (int j = 0; j < 4; ++j) {
        if (have[j]) {
            int b = rec_[j] >> 23;
            int pos = atomicAdd(&lcur[b], 1);
            srec[(excl[b] - hist[b]) + pos] = rec_[j];
        }
    }
    __syncthreads();
    int cnt = N_EDGES - base; if (cnt > SC_EDGES) cnt = SC_EDGES;
    for (int i = t; i < cnt; i += 1024) {            // contiguous run writes
        unsigned int rec = srec[i];
        int b = rec >> 23;
        int gp = gpos[b] + (i - (excl[b] - hist[b]));
        if (gp < SUBCAP)
            recs[((size_t)b * NREP + rep) * SUBCAP + gp] = rec & 0x7fffffu;
    }
}

// one block per bucket: concat 8 sub-segments + inject self-loops -> eids + (start,end)
__global__ __launch_bounds__(256) void bucketize_kernel(
    const unsigned int* __restrict__ recs, const int* __restrict__ bcursor,
    unsigned short* __restrict__ eids, int2* __restrict__ rsre, int n) {
    __shared__ int ssub[NREP + 1];
    __shared__ int hist[128], excl[128], cur[128];
    __shared__ unsigned int srec[EIDS_CAP];          // 10 KB
    int b = blockIdx.x, t = threadIdx.x;
    int nvalid = n - b * 128; if (nvalid > 128) nvalid = 128;
    if (t < 128) { hist[t] = 0; cur[t] = 0; }
    if (t == 0) {
        int run = 0; ssub[0] = 0;
        for (int r = 0; r < NREP; ++r) {
            int c = bcursor[r * NB + b]; if (c > SUBCAP) c = SUBCAP;
            run += c; ssub[r + 1] = run;
        }
    }
    __syncthreads();
    int total = ssub[NREP];
    int maxsc = EIDS_CAP - 128;
    if (total > maxsc) total = maxsc;
    const unsigned int* rb = recs + (size_t)b * NREP * SUBCAP;
    for (int i = t; i < total; i += 256) {
        int r = 0;
        while (ssub[r + 1] <= i) ++r;                // <= 8 steps
        unsigned int rec = rb[r * SUBCAP + (i - ssub[r])];
        srec[i] = rec;
        atomicAdd(&hist[(rec >> 16) & 127], 1);
    }
    __syncthreads();
    if (t < nvalid) hist[t] += 1;                    // self loop
    __syncthreads();
    if (t < 128) excl[t] = hist[t];
    __syncthreads();
    for (int off = 1; off < 128; off <<= 1) {
        int v = 0;
        if (t < 128 && t >= off) v = excl[t - off];
        __syncthreads();
        if (t < 128) excl[t] += v;
        __syncthreads();
    }
    int base2 = b * EIDS_CAP;
    if (t < nvalid) {
        int st = excl[t] - hist[t];
        rsre[b * 128 + t] = make_int2(base2 + st, base2 + excl[t]);
        eids[base2 + st] = (unsigned short)(b * 128 + t);   // self-loop src first
        cur[t] = 1;
    }
    __syncthreads();
    for (int i = t; i < total; i += 256) {
        unsigned int rec = srec[i];
        int dl = (rec >> 16) & 127;
        int pos = atomicAdd(&cur[dl], 1);
        eids[base2 + (excl[dl] - hist[dl]) + pos] = (unsigned short)(rec & 0xffffu);
    }
}

// ---------------- fused MFMA GEMM + attention scalars ----------------

__global__ __launch_bounds__(256) void gemm_fused_f32a_kernel(
    const float* __restrict__ A, const unsigned short* __restrict__ Wt,
    const float* __restrict__ att_s, const float* __restrict__ weffd,
    unsigned short* __restrict__ C, float* __restrict__ a_s, float* __restrict__ a_d, int n) {
    int t = threadIdx.x;
    int l = t & 63;
    int quad = l >> 4, lr = l & 15;
    int m0 = blockIdx.x * 64 + (t >> 6) * 16;
    int arow = m0 + lr; if (arow >= n) arow = n - 1;

    short8 afrag[4];
    float pd0 = 0.f, pd1 = 0.f;
    const float2* wd2 = (const float2*)weffd;
    #pragma unroll
    for (int kb = 0; kb < 4; ++kb) {
        const float4* ap = (const float4*)(A + (size_t)arow * 128 + kb * 32 + quad * 8);
        float4 a0 = ap[0], a1 = ap[1];
        int k0 = kb * 32 + quad * 8;
        float2 w0 = wd2[k0+0], w1 = wd2[k0+1], w2 = wd2[k0+2], w3 = wd2[k0+3];
        float2 w4 = wd2[k0+4], w5 = wd2[k0+5], w6 = wd2[k0+6], w7 = wd2[k0+7];
        pd0 += a0.x*w0.x + a0.y*w1.x + a0.z*w2.x + a0.w*w3.x
             + a1.x*w4.x + a1.y*w5.x + a1.z*w6.x + a1.w*w7.x;
        pd1 += a0.x*w0.y + a0.y*w1.y + a0.z*w2.y + a0.w*w3.y
             + a1.x*w4.y + a1.y*w5.y + a1.z*w6.y + a1.w*w7.y;
        short8 s;
        s[0] = (short)f2bf(a0.x); s[1] = (short)f2bf(a0.y);
        s[2] = (short)f2bf(a0.z); s[3] = (short)f2bf(a0.w);
        s[4] = (short)f2bf(a1.x); s[5] = (short)f2bf(a1.y);
        s[6] = (short)f2bf(a1.z); s[7] = (short)f2bf(a1.w);
        afrag[kb] = s;
    }
    pd0 += __shfl_xor(pd0, 16); pd0 += __shfl_xor(pd0, 32);
    pd1 += __shfl_xor(pd1, 16); pd1 += __shfl_xor(pd1, 32);
    if (l < 16 && m0 + lr < n) *(float2*)(a_d + (size_t)(m0 + lr) * 2) = make_float2(pd0, pd1);

    f32x4 acc[8] = {};
    #pragma unroll
    for (int nt = 0; nt < 8; ++nt) {
        #pragma unroll
        for (int kb = 0; kb < 4; ++kb) {
            short8 b = *(const short8*)(Wt + (size_t)(nt * 16 + lr) * 128 + kb * 32 + quad * 8);
            acc[nt] = __builtin_amdgcn_mfma_f32_16x16x32_bf16(afrag[kb], b, acc[nt], 0, 0, 0);
        }
    }
    float asv[8];
    #pragma unroll
    for (int nt = 0; nt < 8; ++nt) asv[nt] = att_s[nt * 16 + lr];
    float pa0[4] = {}, pa1[4] = {};
    #pragma unroll
    for (int nt = 0; nt < 8; ++nt)
        #pragma unroll
        for (int r = 0; r < 4; ++r) {
            if (nt < 4) pa0[r] += acc[nt][r] * asv[nt];
            else        pa1[r] += acc[nt][r] * asv[nt];
        }
    #pragma unroll
    for (int d = 1; d < 16; d <<= 1) {
        #pragma unroll
        for (int r = 0; r < 4; ++r) {
            pa0[r] += __shfl_xor(pa0[r], d);
            pa1[r] += __shfl_xor(pa1[r], d);
        }
    }
    if (lr == 0) {
        #pragma unroll
        for (int r = 0; r < 4; ++r) {
            int row = m0 + quad * 4 + r;
            if (row < n) *(float2*)(a_s + (size_t)row * 2) = make_float2(pa0[r], pa1[r]);
        }
    }
    #pragma unroll
    for (int nt = 0; nt < 8; ++nt)
        #pragma unroll
        for (int r = 0; r < 4; ++r) {
            int row = m0 + quad * 4 + r;
            if (row < n)
                C[(size_t)row * 128 + nt * 16 + lr] = (unsigned short)f2bf(acc[nt][r]);
        }
}

__global__ __launch_bounds__(256) void gemm_fused_bf16_kernel(
    const unsigned short* __restrict__ A, const unsigned short* __restrict__ Wt,
    const float* __restrict__ att_s, const float* __restrict__ weffd,
    unsigned short* __restrict__ C, float* __restrict__ a_s, float* __restrict__ a_d, int n) {
    int t = threadIdx.x;
    int l = t & 63;
    int quad = l >> 4, lr = l & 15;
    int m0 = blockIdx.x * 64 + (t >> 6) * 16;
    int arow = m0 + lr; if (arow >= n) arow = n - 1;

    short8 afrag[4];
    float pd0 = 0.f, pd1 = 0.f;
    const float2* wd2 = (const float2*)weffd;
    #pragma unroll
    for (int kb = 0; kb < 4; ++kb) {
        short8 s = *(const short8*)(A + (size_t)arow * 128 + kb * 32 + quad * 8);
        afrag[kb] = s;
        const unsigned int* u = (const unsigned int*)&s;
        int k0 = kb * 32 + quad * 8;
        #pragma unroll
        for (int d = 0; d < 4; ++d) {
            float x0 = __uint_as_float(u[d] << 16);
            float x1 = __uint_as_float(u[d] & 0xffff0000u);
            float2 wv0 = wd2[k0 + 2*d], wv1 = wd2[k0 + 2*d + 1];
            pd0 += x0 * wv0.x + x1 * wv1.x;
            pd1 += x0 * wv0.y + x1 * wv1.y;
        }
    }
    pd0 += __shfl_xor(pd0, 16); pd0 += __shfl_xor(pd0, 32);
    pd1 += __shfl_xor(pd1, 16); pd1 += __shfl_xor(pd1, 32);
    if (l < 16 && m0 + lr < n) *(float2*)(a_d + (size_t)(m0 + lr) * 2) = make_float2(pd0, pd1);

    f32x4 acc[8] = {};
    #pragma unroll
    for (int nt = 0; nt < 8; ++nt) {
        #pragma unroll
        for (int kb = 0; kb < 4; ++kb) {
            short8 b = *(const short8*)(Wt + (size_t)(nt * 16 + lr) * 128 + kb * 32 + quad * 8);
            acc[nt] = __builtin_amdgcn_mfma_f32_16x16x32_bf16(afrag[kb], b, acc[nt], 0, 0, 0);
        }
    }
    float asv[8];
    #pragma unroll
    for (int nt = 0; nt < 8; ++nt) asv[nt] = att_s[nt * 16 + lr];
    float pa0[4] = {}, pa1[4] = {};
    #pragma unroll
    for (int nt = 0; nt < 8; ++nt)
        #pragma unroll
        for (int r = 0; r < 4; ++r) {
            if (nt < 4) pa0[r] += acc[nt][r] * asv[nt];
            else        pa1[r] += acc[nt][r] * asv[nt];
        }
    #pragma unroll
    for (int d = 1; d < 16; d <<= 1) {
        #pragma unroll
        for (int r = 0; r < 4; ++r) {
            pa0[r] += __shfl_xor(pa0[r], d);
            pa1[r] += __shfl_xor(pa1[r], d);
        }
    }
    if (lr == 0) {
        #pragma unroll
        for (int r = 0; r < 4; ++r) {
            int row = m0 + quad * 4 + r;
            if (row < n) *(float2*)(a_s + (size_t)row * 2) = make_float2(pa0[r], pa1[r]);
        }
    }
    #pragma unroll
    for (int nt = 0; nt < 8; ++nt)
        #pragma unroll
        for (int r = 0; r < 4; ++r) {
            int row = m0 + quad * 4 + r;
            if (row < n)
                C[(size_t)row * 128 + nt * 16 + lr] = (unsigned short)f2bf(acc[nt][r]);
        }
}

// ---------------- edge aggregation: one wave per destination node ----------------

__global__ __launch_bounds__(256) void aggregate_kernel(
    const int2* __restrict__ rsre, const unsigned short* __restrict__ eids,
    const float* __restrict__ a_s, const float* __restrict__ a_d,
    const unsigned int* __restrict__ xs32, const float* __restrict__ bias,
    unsigned int* __restrict__ out32, int n) {
    int wave = (int)((blockIdx.x * blockDim.x + threadIdx.x) >> 6);
    int lane = threadIdx.x & 63;
    if (wave >= n) return;
    int dstn = wave;
    int h    = lane >> 5;
    int j32  = lane & 31;
    int hoff = h << 5;
    int ch   = lane * 2;
    float2 advv = *(const float2*)(a_d + (size_t)dstn * 2);
    float adv = (h == 0) ? advv.x : advv.y;
    int2 rr = rsre[dstn];
    int row = rr.x, end = rr.y;

    float accA0 = 0.f, accA1 = 0.f, accB0 = 0.f, accB1 = 0.f, lsum = 0.f;
    for (int base = row; base < end; base += 32) {
        int rem = end - base;
        int k = rem < 32 ? rem : 32;
        int idx = base + (j32 < k ? j32 : k - 1);
        int eidv = (int)eids[idx];
        float2 as2 = *(const float2*)(a_s + (size_t)eidv * 2);
        float e = ((h == 0) ? as2.x : as2.y) + adv;
        e = (e > 0.f) ? e : 0.2f * e;
        float pme = (j32 < k) ? __expf(e) : 0.f;
        lsum += pme;
        int jb = 0;
        for (; jb + 4 <= k; jb += 4) {
            #pragma unroll
            for (int u = 0; u < 4; ++u) {
                int j = jb + u;
                int srcn = __shfl(eidv, j);
                float pj = __shfl(pme, j + hoff);
                unsigned int v = xs32[(size_t)srcn * 64 + lane];
                if (u & 1) {
                    accB0 += pj * __uint_as_float(v << 16);
                    accB1 += pj * __uint_as_float(v & 0xffff0000u);
                } else {
                    accA0 += pj * __uint_as_float(v << 16);
                    accA1 += pj * __uint_as_float(v & 0xffff0000u);
                }
            }
        }
        for (; jb < k; ++jb) {
            int srcn = __shfl(eidv, jb);
            float pj = __shfl(pme, jb + hoff);
            unsigned int v = xs32[(size_t)srcn * 64 + lane];
            accA0 += pj * __uint_as_float(v << 16);
            accA1 += pj * __uint_as_float(v & 0xffff0000u);
        }
    }
    #pragma unroll
    for (int d = 1; d <= 16; d <<= 1) lsum += __shfl_xor(lsum, d);
    float inv = 1.f / lsum;
    float o0 = fmaxf((accA0 + accB0) * inv + bias[ch], 0.f);
    float o1 = fmaxf((accA1 + accB1) * inv + bias[ch + 1], 0.f);
    out32[(size_t)dstn * 64 + lane] = f2bf(o0) | (f2bf(o1) << 16);
}

// ---------------- pool: partial sums + tiny final linear ----------------

#define POOL_CHUNK 128

__global__ __launch_bounds__(256) void pool_partial_kernel(
    const unsigned short* __restrict__ Hf, const int* __restrict__ batch,
    float* __restrict__ sums, int n) {
    int t = threadIdx.x;
    int c = t & 127, half = t >> 7;
    int start = blockIdx.x * POOL_CHUNK;
    int end = min(start + POOL_CHUNK, n);
    float acc = 0.f;
    int cur = -1;
    for (int i = start + half; i < end; i += 2) {
        int g = batch[i];
        if (g != cur) {
            if (cur >= 0) atomicAdd(&sums[cur * 128 + c], acc);
            acc = 0.f; cur = g;
        }
        acc += bf2f(Hf[(size_t)i * 128 + c]);
    }
    if (cur >= 0) atomicAdd(&sums[cur * 128 + c], acc);
}

__global__ void final_linear_kernel(const float* __restrict__ sums,
                                    const int* __restrict__ batch,
                                    const float* __restrict__ Wl, const float* __restrict__ bl,
                                    float* __restrict__ out, int n) {
    int t = blockIdx.x * blockDim.x + threadIdx.x;
    if (t >= N_GRAPHS * OUT_DIM) return;
    int g = t / OUT_DIM, o = t % OUT_DIM;
    int lo = 0, hi = n;
    while (lo < hi) { int mid = (lo + hi) >> 1; if (batch[mid] < g) lo = mid + 1; else hi = mid; }
    int s0 = lo; hi = n;
    while (lo < hi) { int mid = (lo + hi) >> 1; if (batch[mid] < g + 1) lo = mid + 1; else hi = mid; }
    float cnt = (float)(lo - s0);
    float inv = 1.f / fmaxf(cnt, 1.f);
    float s = bl[o];
    for (int c = 0; c < 128; ++c) s += sums[g * 128 + c] * inv * Wl[c * OUT_DIM + o];
    out[g * OUT_DIM + o] = s;
}

// ---------------- launch ----------------

extern "C" void kernel_launch(void* const* d_in, const int* in_sizes, int n_in,
                              void* d_out, int out_size, void* d_ws, size_t ws_size,
                              hipStream_t stream) {
    const float* x    = (const float*)d_in[0];
    const int*   ei   = (const int*)d_in[1];
    const int*   batch= (const int*)d_in[2];
    const float* Ws1  = (const float*)d_in[3];
    const float* Wd1  = (const float*)d_in[4];
    const float* as1  = (const float*)d_in[5];
    const float* ad1  = (const float*)d_in[6];
    const float* b1   = (const float*)d_in[7];
    const float* Ws2  = (const float*)d_in[8];
    const float* Wd2  = (const float*)d_in[9];
    const float* as2  = (const float*)d_in[10];
    const float* ad2  = (const float*)d_in[11];
    const float* b2   = (const float*)d_in[12];
    const float* Wl   = (const float*)d_in[13];
    const float* bl   = (const float*)d_in[14];
    float* out = (float*)d_out;

    // Workspace ~29 MB total (R8's 32.5 MB passed; R9's 42.7 MB aborted).
    char* p = (char*)d_ws;
    auto alloc = [&](size_t bytes) {
        void* r = (void*)p;
        p += (bytes + 255) & ~(size_t)255;
        return r;
    };
    int* bcursor  = (int*)alloc(sizeof(int) * NREP * NB);                      // 12.5 KB
    unsigned short* eids = (unsigned short*)alloc(sizeof(short) * (size_t)NB * EIDS_CAP); // 2.0 MB
    int2* rsre    = (int2*)alloc(sizeof(int2) * N_NODES);
    float* a_s    = (float*)alloc(sizeof(float) * N_NODES * 2);
    float* a_d    = (float*)alloc(sizeof(float) * N_NODES * 2);
    float* sums   = (float*)alloc(sizeof(float) * N_GRAPHS * 128);
    float* weffd1 = (float*)alloc(sizeof(float) * 128 * 2);
    float* weffd2 = (float*)alloc(sizeof(float) * 128 * 2);
    unsigned short* Wt1  = (unsigned short*)alloc(sizeof(short) * 128 * 128);
    unsigned short* Wt2  = (unsigned short*)alloc(sizeof(short) * 128 * 128);
    unsigned short* bufA = (unsigned short*)alloc(sizeof(short) * (size_t)N_NODES * F_DIM);
    unsigned short* bufB = (unsigned short*)alloc(sizeof(short) * (size_t)N_NODES * F_DIM);
    // recs (NB*NREP*SUBCAP*4 = 4.6 MB) aliases bufA: dead before gemm1 writes bufA.
    unsigned int* recs = (unsigned int*)bufA;

    // ---- prep + CSR build ----
    prep_kernel<<<128, 256, 0, stream>>>(Ws1, Ws2, Wd1, ad1, Wd2, ad2,
                                         Wt1, Wt2, weffd1, weffd2,
                                         (uint4*)bcursor, (uint4*)sums);
    scatter_kernel<<<SC_BLOCKS, 1024, 0, stream>>>(ei, bcursor, recs);
    bucketize_kernel<<<NB, 256, 0, stream>>>(recs, bcursor, eids, rsre, N_NODES);

    const int gemm_grid = (N_NODES + 63) / 64;
    const int agg_grid  = (N_NODES + 3) / 4;

    // ---- layer 1 ----
    gemm_fused_f32a_kernel<<<gemm_grid, 256, 0, stream>>>(x, Wt1, as1, weffd1,
                                                          bufA, a_s, a_d, N_NODES);
    aggregate_kernel<<<agg_grid, 256, 0, stream>>>(rsre, eids, a_s, a_d,
                                                   (const unsigned int*)bufA, b1,
                                                   (unsigned int*)bufB, N_NODES);

    // ---- layer 2 ----
    gemm_fused_bf16_kernel<<<gemm_grid, 256, 0, stream>>>(bufB, Wt2, as2, weffd2,
                                                          bufA, a_s, a_d, N_NODES);
    aggregate_kernel<<<agg_grid, 256, 0, stream>>>(rsre, eids, a_s, a_d,
                                                   (const unsigned int*)bufA, b2,
                                                   (unsigned int*)bufB, N_NODES);

    // ---- pool + linear ----
    pool_partial_kernel<<<(N_NODES + POOL_CHUNK - 1) / POOL_CHUNK, 256, 0, stream>>>(bufB, batch, sums, N_NODES);
    final_linear_kernel<<<(N_GRAPHS * OUT_DIM + 255) / 256, 256, 0, stream>>>(sums, batch, Wl, bl, out, N_NODES);
}

// Round 12
// 275.668 us; speedup vs baseline: 2.1346x; 1.0072x over previous
//
#include <hip/hip_runtime.h>
#include <hip/hip_bf16.h>

#define N_NODES 50000
#define N_EDGES 800000
#define EP (N_EDGES + N_NODES)
#define N_GRAPHS 64
#define F_DIM 128
#define OUT_DIM 10
#define NB 391                   // dst buckets of 128
#define NREP 8                   // cursor replicas: rep = blockIdx & 7
#define SUBCAP 384               // per (bucket,rep): E=256, +8 sigma
#define EIDS_CAP 2560            // per-bucket: E=2174 (incl selfloops), +8.6 sigma
#define SC_EDGES 4096            // edges per scatter block
#define SC_BLOCKS ((N_EDGES + SC_EDGES - 1) / SC_EDGES)   // 196

typedef __attribute__((ext_vector_type(8))) short short8;
typedef __attribute__((ext_vector_type(4))) float f32x4;

__device__ __forceinline__ unsigned int f2bf(float f) {
    unsigned int x; __builtin_memcpy(&x, &f, 4);
    return (x + 0x7fffu + ((x >> 16) & 1u)) >> 16;          // RNE
}
__device__ __forceinline__ float bf2f(unsigned int u16) {
    unsigned int x = u16 << 16;
    float f; __builtin_memcpy(&f, &x, 4); return f;
}

// ---------------- prep: zeros + W->Wt casts + weff_d ----------------

__global__ __launch_bounds__(256) void prep_kernel(
    const float* __restrict__ W1, const float* __restrict__ W2,
    const float* __restrict__ Wd1, const float* __restrict__ ad1,
    const float* __restrict__ Wd2, const float* __restrict__ ad2,
    unsigned short* __restrict__ Wt1, unsigned short* __restrict__ Wt2,
    float* __restrict__ weffd1, float* __restrict__ weffd2,
    uint4* __restrict__ zero_bcur /*782*/, uint4* __restrict__ zero_sums /*2048*/) {
    int tid = blockIdx.x * 256 + threadIdx.x;
    if (tid < 782) zero_bcur[tid] = make_uint4(0, 0, 0, 0);
    else if (tid < 782 + 2048) zero_sums[tid - 782] = make_uint4(0, 0, 0, 0);
    if (tid < 512) {
        const float* Wd = (tid < 256) ? Wd1 : Wd2;
        const float* ad = (tid < 256) ? ad1 : ad2;
        float* wout = (tid < 256) ? weffd1 : weffd2;
        int i = tid & 255, f = i >> 1, h = i & 1;
        const float4* wr = (const float4*)(Wd + f * 128 + h * 64);
        const float4* av = (const float4*)(ad + h * 64);
        float s = 0.f;
        #pragma unroll
        for (int c = 0; c < 16; ++c) {
            float4 w = wr[c], a = av[c];
            s += w.x*a.x + w.y*a.y + w.z*a.z + w.w*a.w;
        }
        wout[f * 2 + h] = s;
    }
    const float* W = (tid < 16384) ? W1 : W2;
    unsigned short* Wt = (tid < 16384) ? Wt1 : Wt2;
    int i = tid & 16383;
    int k = i >> 7, nn = i & 127;
    Wt[nn * 128 + k] = (unsigned short)f2bf(W[i]);
}

// ---------------- CSR build: LDS counting-sort scatter (coalesced run writes) ----------------

__global__ __launch_bounds__(1024) void scatter_kernel(const int* __restrict__ ei,
                                                       int* __restrict__ bcursor,
                                                       unsigned int* __restrict__ recs) {
    __shared__ unsigned int srec[SC_EDGES];   // 16 KB
    __shared__ int hist[NB], lcur[NB], gpos[NB];
    __shared__ int excl[512];
    int t = threadIdx.x;
    int base = blockIdx.x * SC_EDGES;
    int rep = blockIdx.x & (NREP - 1);
    for (int i = t; i < NB; i += 1024) { hist[i] = 0; lcur[i] = 0; }
    __syncthreads();
    unsigned int rec_[4]; int have[4];
    #pragma unroll
    for (int j = 0; j < 4; ++j) {
        int i = base + j * 1024 + t;
        have[j] = (i < N_EDGES);
        if (have[j]) {
            int src = ei[i], dst = ei[N_EDGES + i];
            int b = dst >> 7;
            rec_[j] = ((unsigned)b << 23) | ((unsigned)(dst & 127) << 16) | (unsigned)src;
            atomicAdd(&hist[b], 1);
        }
    }
    __syncthreads();
    if (t < 512) excl[t] = (t < NB) ? hist[t] : 0;
    __syncthreads();
    for (int off = 1; off < 512; off <<= 1) {
        int v = 0;
        if (t < 512 && t >= off) v = excl[t - off];
        __syncthreads();
        if (t < 512) excl[t] += v;
        __syncthreads();
    }
    if (t < NB && hist[t] > 0) gpos[t] = atomicAdd(&bcursor[rep * NB + t], hist[t]);
    __syncthreads();
    #pragma unroll
    for (int j = 0; j < 4; ++j) {
        if (have[j]) {
            int b = rec_[j] >> 23;
            int pos = atomicAdd(&lcur[b], 1);
            srec[(excl[b] - hist[b]) + pos] = rec_[j];
        }
    }
    __syncthreads();
    int cnt = N_EDGES - base; if (cnt > SC_EDGES) cnt = SC_EDGES;
    for (int i = t; i < cnt; i += 1024) {
        unsigned int rec = srec[i];
        int b = rec >> 23;
        int gp = gpos[b] + (i - (excl[b] - hist[b]));
        if (gp < SUBCAP)
            recs[((size_t)b * NREP + rep) * SUBCAP + gp] = rec & 0x7fffffu;
    }
}

// one block per bucket: concat 8 sub-segments + inject self-loops -> eids + (start,end)
__global__ __launch_bounds__(256) void bucketize_kernel(
    const unsigned int* __restrict__ recs, const int* __restrict__ bcursor,
    unsigned short* __restrict__ eids, int2* __restrict__ rsre, int n) {
    __shared__ int ssub[NREP + 1];
    __shared__ int hist[128], excl[128], cur[128];
    __shared__ unsigned int srec[EIDS_CAP];
    int b = blockIdx.x, t = threadIdx.x;
    int nvalid = n - b * 128; if (nvalid > 128) nvalid = 128;
    if (t < 128) { hist[t] = 0; cur[t] = 0; }
    if (t == 0) {
        int run = 0; ssub[0] = 0;
        for (int r = 0; r < NREP; ++r) {
            int c = bcursor[r * NB + b]; if (c > SUBCAP) c = SUBCAP;
            run += c; ssub[r + 1] = run;
        }
    }
    __syncthreads();
    int total = ssub[NREP];
    int maxsc = EIDS_CAP - 128;
    if (total > maxsc) total = maxsc;
    const unsigned int* rb = recs + (size_t)b * NREP * SUBCAP;
    for (int i = t; i < total; i += 256) {
        int r = 0;
        while (ssub[r + 1] <= i) ++r;
        unsigned int rec = rb[r * SUBCAP + (i - ssub[r])];
        srec[i] = rec;
        atomicAdd(&hist[(rec >> 16) & 127], 1);
    }
    __syncthreads();
    if (t < nvalid) hist[t] += 1;                    // self loop
    __syncthreads();
    if (t < 128) excl[t] = hist[t];
    __syncthreads();
    for (int off = 1; off < 128; off <<= 1) {
        int v = 0;
        if (t < 128 && t >= off) v = excl[t - off];
        __syncthreads();
        if (t < 128) excl[t] += v;
        __syncthreads();
    }
    int base2 = b * EIDS_CAP;
    if (t < nvalid) {
        int st = excl[t] - hist[t];
        rsre[b * 128 + t] = make_int2(base2 + st, base2 + excl[t]);
        eids[base2 + st] = (unsigned short)(b * 128 + t);
        cur[t] = 1;
    }
    __syncthreads();
    for (int i = t; i < total; i += 256) {
        unsigned int rec = srec[i];
        int dl = (rec >> 16) & 127;
        int pos = atomicAdd(&cur[dl], 1);
        eids[base2 + (excl[dl] - hist[dl]) + pos] = (unsigned short)(rec & 0xffffu);
    }
}

// ---------------- fused MFMA GEMM + attention scalars ----------------

__global__ __launch_bounds__(256) void gemm_fused_f32a_kernel(
    const float* __restrict__ A, const unsigned short* __restrict__ Wt,
    const float* __restrict__ att_s, const float* __restrict__ weffd,
    unsigned short* __restrict__ C, float* __restrict__ a_s, float* __restrict__ a_d, int n) {
    int t = threadIdx.x;
    int l = t & 63;
    int quad = l >> 4, lr = l & 15;
    int m0 = blockIdx.x * 64 + (t >> 6) * 16;
    int arow = m0 + lr; if (arow >= n) arow = n - 1;

    short8 afrag[4];
    float pd0 = 0.f, pd1 = 0.f;
    const float2* wd2 = (const float2*)weffd;
    #pragma unroll
    for (int kb = 0; kb < 4; ++kb) {
        const float4* ap = (const float4*)(A + (size_t)arow * 128 + kb * 32 + quad * 8);
        float4 a0 = ap[0], a1 = ap[1];
        int k0 = kb * 32 + quad * 8;
        float2 w0 = wd2[k0+0], w1 = wd2[k0+1], w2 = wd2[k0+2], w3 = wd2[k0+3];
        float2 w4 = wd2[k0+4], w5 = wd2[k0+5], w6 = wd2[k0+6], w7 = wd2[k0+7];
        pd0 += a0.x*w0.x + a0.y*w1.x + a0.z*w2.x + a0.w*w3.x
             + a1.x*w4.x + a1.y*w5.x + a1.z*w6.x + a1.w*w7.x;
        pd1 += a0.x*w0.y + a0.y*w1.y + a0.z*w2.y + a0.w*w3.y
             + a1.x*w4.y + a1.y*w5.y + a1.z*w6.y + a1.w*w7.y;
        short8 s;
        s[0] = (short)f2bf(a0.x); s[1] = (short)f2bf(a0.y);
        s[2] = (short)f2bf(a0.z); s[3] = (short)f2bf(a0.w);
        s[4] = (short)f2bf(a1.x); s[5] = (short)f2bf(a1.y);
        s[6] = (short)f2bf(a1.z); s[7] = (short)f2bf(a1.w);
        afrag[kb] = s;
    }
    pd0 += __shfl_xor(pd0, 16); pd0 += __shfl_xor(pd0, 32);
    pd1 += __shfl_xor(pd1, 16); pd1 += __shfl_xor(pd1, 32);
    if (l < 16 && m0 + lr < n) *(float2*)(a_d + (size_t)(m0 + lr) * 2) = make_float2(pd0, pd1);

    f32x4 acc[8] = {};
    #pragma unroll
    for (int nt = 0; nt < 8; ++nt) {
        #pragma unroll
        for (int kb = 0; kb < 4; ++kb) {
            short8 b = *(const short8*)(Wt + (size_t)(nt * 16 + lr) * 128 + kb * 32 + quad * 8);
            acc[nt] = __builtin_amdgcn_mfma_f32_16x16x32_bf16(afrag[kb], b, acc[nt], 0, 0, 0);
        }
    }
    float asv[8];
    #pragma unroll
    for (int nt = 0; nt < 8; ++nt) asv[nt] = att_s[nt * 16 + lr];
    float pa0[4] = {}, pa1[4] = {};
    #pragma unroll
    for (int nt = 0; nt < 8; ++nt)
        #pragma unroll
        for (int r = 0; r < 4; ++r) {
            if (nt < 4) pa0[r] += acc[nt][r] * asv[nt];
            else        pa1[r] += acc[nt][r] * asv[nt];
        }
    #pragma unroll
    for (int d = 1; d < 16; d <<= 1) {
        #pragma unroll
        for (int r = 0; r < 4; ++r) {
            pa0[r] += __shfl_xor(pa0[r], d);
            pa1[r] += __shfl_xor(pa1[r], d);
        }
    }
    if (lr == 0) {
        #pragma unroll
        for (int r = 0; r < 4; ++r) {
            int row = m0 + quad * 4 + r;
            if (row < n) *(float2*)(a_s + (size_t)row * 2) = make_float2(pa0[r], pa1[r]);
        }
    }
    #pragma unroll
    for (int nt = 0; nt < 8; ++nt)
        #pragma unroll
        for (int r = 0; r < 4; ++r) {
            int row = m0 + quad * 4 + r;
            if (row < n)
                C[(size_t)row * 128 + nt * 16 + lr] = (unsigned short)f2bf(acc[nt][r]);
        }
}

__global__ __launch_bounds__(256) void gemm_fused_bf16_kernel(
    const unsigned short* __restrict__ A, const unsigned short* __restrict__ Wt,
    const float* __restrict__ att_s, const float* __restrict__ weffd,
    unsigned short* __restrict__ C, float* __restrict__ a_s, float* __restrict__ a_d, int n) {
    int t = threadIdx.x;
    int l = t & 63;
    int quad = l >> 4, lr = l & 15;
    int m0 = blockIdx.x * 64 + (t >> 6) * 16;
    int arow = m0 + lr; if (arow >= n) arow = n - 1;

    short8 afrag[4];
    float pd0 = 0.f, pd1 = 0.f;
    const float2* wd2 = (const float2*)weffd;
    #pragma unroll
    for (int kb = 0; kb < 4; ++kb) {
        short8 s = *(const short8*)(A + (size_t)arow * 128 + kb * 32 + quad * 8);
        afrag[kb] = s;
        const unsigned int* u = (const unsigned int*)&s;
        int k0 = kb * 32 + quad * 8;
        #pragma unroll
        for (int d = 0; d < 4; ++d) {
            float x0 = __uint_as_float(u[d] << 16);
            float x1 = __uint_as_float(u[d] & 0xffff0000u);
            float2 wv0 = wd2[k0 + 2*d], wv1 = wd2[k0 + 2*d + 1];
            pd0 += x0 * wv0.x + x1 * wv1.x;
            pd1 += x0 * wv0.y + x1 * wv1.y;
        }
    }
    pd0 += __shfl_xor(pd0, 16); pd0 += __shfl_xor(pd0, 32);
    pd1 += __shfl_xor(pd1, 16); pd1 += __shfl_xor(pd1, 32);
    if (l < 16 && m0 + lr < n) *(float2*)(a_d + (size_t)(m0 + lr) * 2) = make_float2(pd0, pd1);

    f32x4 acc[8] = {};
    #pragma unroll
    for (int nt = 0; nt < 8; ++nt) {
        #pragma unroll
        for (int kb = 0; kb < 4; ++kb) {
            short8 b = *(const short8*)(Wt + (size_t)(nt * 16 + lr) * 128 + kb * 32 + quad * 8);
            acc[nt] = __builtin_amdgcn_mfma_f32_16x16x32_bf16(afrag[kb], b, acc[nt], 0, 0, 0);
        }
    }
    float asv[8];
    #pragma unroll
    for (int nt = 0; nt < 8; ++nt) asv[nt] = att_s[nt * 16 + lr];
    float pa0[4] = {}, pa1[4] = {};
    #pragma unroll
    for (int nt = 0; nt < 8; ++nt)
        #pragma unroll
        for (int r = 0; r < 4; ++r) {
            if (nt < 4) pa0[r] += acc[nt][r] * asv[nt];
            else        pa1[r] += acc[nt][r] * asv[nt];
        }
    #pragma unroll
    for (int d = 1; d < 16; d <<= 1) {
        #pragma unroll
        for (int r = 0; r < 4; ++r) {
            pa0[r] += __shfl_xor(pa0[r], d);
            pa1[r] += __shfl_xor(pa1[r], d);
        }
    }
    if (lr == 0) {
        #pragma unroll
        for (int r = 0; r < 4; ++r) {
            int row = m0 + quad * 4 + r;
            if (row < n) *(float2*)(a_s + (size_t)row * 2) = make_float2(pa0[r], pa1[r]);
        }
    }
    #pragma unroll
    for (int nt = 0; nt < 8; ++nt)
        #pragma unroll
        for (int r = 0; r < 4; ++r) {
            int row = m0 + quad * 4 + r;
            if (row < n)
                C[(size_t)row * 128 + nt * 16 + lr] = (unsigned short)f2bf(acc[nt][r]);
        }
}

// ---------------- edge aggregation: one wave per destination node ----------------
// 32-edge chunks with next-chunk eids prefetch; lanes 0-31 head-0 exp, 32-63 head-1;
// unroll 8 (8 gathers in flight); unstabilized softmax.

__global__ __launch_bounds__(256) void aggregate_kernel(
    const int2* __restrict__ rsre, const unsigned short* __restrict__ eids,
    const float* __restrict__ a_s, const float* __restrict__ a_d,
    const unsigned int* __restrict__ xs32, const float* __restrict__ bias,
    unsigned int* __restrict__ out32, int n) {
    int wave = (int)((blockIdx.x * blockDim.x + threadIdx.x) >> 6);
    int lane = threadIdx.x & 63;
    if (wave >= n) return;
    int dstn = wave;
    int h    = lane >> 5;
    int j32  = lane & 31;
    int hoff = h << 5;
    int ch   = lane * 2;
    float2 advv = *(const float2*)(a_d + (size_t)dstn * 2);
    float adv = (h == 0) ? advv.x : advv.y;
    int2 rr = rsre[dstn];
    int row = rr.x, end = rr.y;

    float aA0 = 0.f, aA1 = 0.f, aB0 = 0.f, aB1 = 0.f, lsum = 0.f;
    int k = end - row; if (k > 32) k = 32;
    int eidv = (int)eids[row + (j32 < k ? j32 : k - 1)];
    for (int base = row; base < end; ) {
        // prefetch next chunk's eids while this chunk computes
        int nbase = base + 32;
        int nk = end - nbase; if (nk > 32) nk = 32;
        int neidv = eidv;
        if (nbase < end) neidv = (int)eids[nbase + (j32 < nk ? j32 : nk - 1)];

        float2 as2 = *(const float2*)(a_s + (size_t)eidv * 2);
        float e = ((h == 0) ? as2.x : as2.y) + adv;
        e = (e > 0.f) ? e : 0.2f * e;
        float pme = (j32 < k) ? __expf(e) : 0.f;
        lsum += pme;
        int jb = 0;
        for (; jb + 8 <= k; jb += 8) {
            #pragma unroll
            for (int u = 0; u < 8; ++u) {
                int j = jb + u;
                int srcn = __shfl(eidv, j);
                float pj = __shfl(pme, j + hoff);
                unsigned int v = xs32[(size_t)srcn * 64 + lane];
                float v0 = __uint_as_float(v << 16);
                float v1 = __uint_as_float(v & 0xffff0000u);
                if (u & 1) { aB0 += pj * v0; aB1 += pj * v1; }
                else       { aA0 += pj * v0; aA1 += pj * v1; }
            }
        }
        for (; jb < k; ++jb) {
            int srcn = __shfl(eidv, jb);
            float pj = __shfl(pme, jb + hoff);
            unsigned int v = xs32[(size_t)srcn * 64 + lane];
            aA0 += pj * __uint_as_float(v << 16);
            aA1 += pj * __uint_as_float(v & 0xffff0000u);
        }
        base = nbase; k = nk; eidv = neidv;
    }
    #pragma unroll
    for (int d = 1; d <= 16; d <<= 1) lsum += __shfl_xor(lsum, d);
    float inv = 1.f / lsum;
    float o0 = fmaxf((aA0 + aB0) * inv + bias[ch], 0.f);
    float o1 = fmaxf((aA1 + aB1) * inv + bias[ch + 1], 0.f);
    out32[(size_t)dstn * 64 + lane] = f2bf(o0) | (f2bf(o1) << 16);
}

// ---------------- pool: partial sums + tiny final linear ----------------

#define POOL_CHUNK 128

__global__ __launch_bounds__(256) void pool_partial_kernel(
    const unsigned short* __restrict__ Hf, const int* __restrict__ batch,
    float* __restrict__ sums, int n) {
    int t = threadIdx.x;
    int c = t & 127, half = t >> 7;
    int start = blockIdx.x * POOL_CHUNK;
    int end = min(start + POOL_CHUNK, n);
    float acc = 0.f;
    int cur = -1;
    for (int i = start + half; i < end; i += 2) {
        int g = batch[i];
        if (g != cur) {
            if (cur >= 0) atomicAdd(&sums[cur * 128 + c], acc);
            acc = 0.f; cur = g;
        }
        acc += bf2f(Hf[(size_t)i * 128 + c]);
    }
    if (cur >= 0) atomicAdd(&sums[cur * 128 + c], acc);
}

__global__ void final_linear_kernel(const float* __restrict__ sums,
                                    const int* __restrict__ batch,
                                    const float* __restrict__ Wl, const float* __restrict__ bl,
                                    float* __restrict__ out, int n) {
    int t = blockIdx.x * blockDim.x + threadIdx.x;
    if (t >= N_GRAPHS * OUT_DIM) return;
    int g = t / OUT_DIM, o = t % OUT_DIM;
    int lo = 0, hi = n;
    while (lo < hi) { int mid = (lo + hi) >> 1; if (batch[mid] < g) lo = mid + 1; else hi = mid; }
    int s0 = lo; hi = n;
    while (lo < hi) { int mid = (lo + hi) >> 1; if (batch[mid] < g + 1) lo = mid + 1; else hi = mid; }
    float cnt = (float)(lo - s0);
    float inv = 1.f / fmaxf(cnt, 1.f);
    float s = bl[o];
    for (int c = 0; c < 128; ++c) s += sums[g * 128 + c] * inv * Wl[c * OUT_DIM + o];
    out[g * OUT_DIM + o] = s;
}

// ---------------- launch ----------------

extern "C" void kernel_launch(void* const* d_in, const int* in_sizes, int n_in,
                              void* d_out, int out_size, void* d_ws, size_t ws_size,
                              hipStream_t stream) {
    const float* x    = (const float*)d_in[0];
    const int*   ei   = (const int*)d_in[1];
    const int*   batch= (const int*)d_in[2];
    const float* Ws1  = (const float*)d_in[3];
    const float* Wd1  = (const float*)d_in[4];
    const float* as1  = (const float*)d_in[5];
    const float* ad1  = (const float*)d_in[6];
    const float* b1   = (const float*)d_in[7];
    const float* Ws2  = (const float*)d_in[8];
    const float* Wd2  = (const float*)d_in[9];
    const float* as2  = (const float*)d_in[10];
    const float* ad2  = (const float*)d_in[11];
    const float* b2   = (const float*)d_in[12];
    const float* Wl   = (const float*)d_in[13];
    const float* bl   = (const float*)d_in[14];
    float* out = (float*)d_out;

    char* p = (char*)d_ws;
    auto alloc = [&](size_t bytes) {
        void* r = (void*)p;
        p += (bytes + 255) & ~(size_t)255;
        return r;
    };
    int* bcursor  = (int*)alloc(sizeof(int) * NREP * NB);
    unsigned short* eids = (unsigned short*)alloc(sizeof(short) * (size_t)NB * EIDS_CAP);
    int2* rsre    = (int2*)alloc(sizeof(int2) * N_NODES);
    float* a_s    = (float*)alloc(sizeof(float) * N_NODES * 2);
    float* a_d    = (float*)alloc(sizeof(float) * N_NODES * 2);
    float* sums   = (float*)alloc(sizeof(float) * N_GRAPHS * 128);
    float* weffd1 = (float*)alloc(sizeof(float) * 128 * 2);
    float* weffd2 = (float*)alloc(sizeof(float) * 128 * 2);
    unsigned short* Wt1  = (unsigned short*)alloc(sizeof(short) * 128 * 128);
    unsigned short* Wt2  = (unsigned short*)alloc(sizeof(short) * 128 * 128);
    unsigned short* bufA = (unsigned short*)alloc(sizeof(short) * (size_t)N_NODES * F_DIM);
    unsigned short* bufB = (unsigned short*)alloc(sizeof(short) * (size_t)N_NODES * F_DIM);
    // recs (NB*NREP*SUBCAP*4 = 4.6 MB) aliases bufA: dead before gemm1 writes bufA.
    unsigned int* recs = (unsigned int*)bufA;

    // ---- prep + CSR build ----
    prep_kernel<<<128, 256, 0, stream>>>(Ws1, Ws2, Wd1, ad1, Wd2, ad2,
                                         Wt1, Wt2, weffd1, weffd2,
                                         (uint4*)bcursor, (uint4*)sums);
    scatter_kernel<<<SC_BLOCKS, 1024, 0, stream>>>(ei, bcursor, recs);
    bucketize_kernel<<<NB, 256, 0, stream>>>(recs, bcursor, eids, rsre, N_NODES);

    const int gemm_grid = (N_NODES + 63) / 64;
    const int agg_grid  = (N_NODES + 3) / 4;

    // ---- layer 1 ----
    gemm_fused_f32a_kernel<<<gemm_grid, 256, 0, stream>>>(x, Wt1, as1, weffd1,
                                                          bufA, a_s, a_d, N_NODES);
    aggregate_kernel<<<agg_grid, 256, 0, stream>>>(rsre, eids, a_s, a_d,
                                                   (const unsigned int*)bufA, b1,
                                                   (unsigned int*)bufB, N_NODES);

    // ---- layer 2 ----
    gemm_fused_bf16_kernel<<<gemm_grid, 256, 0, stream>>>(bufB, Wt2, as2, weffd2,
                                                          bufA, a_s, a_d, N_NODES);
    aggregate_kernel<<<agg_grid, 256, 0, stream>>>(rsre, eids, a_s, a_d,
                                                   (const unsigned int*)bufA, b2,
                                                   (unsigned int*)bufB, N_NODES);

    // ---- pool + linear ----
    pool_partial_kernel<<<(N_NODES + POOL_CHUNK - 1) / POOL_CHUNK, 256, 0, stream>>>(bufB, batch, sums, N_NODES);
    final_linear_kernel<<<(N_GRAPHS * OUT_DIM + 255) / 256, 256, 0, stream>>>(sums, batch, Wl, bl, out, N_NODES);
}